// Round 6
// baseline (413.178 us; speedup 1.0000x reference)
//
#include <hip/hip_runtime.h>
#include <math.h>

// ---- problem constants ----
#define NB      8
#define C_IN    3
#define HIMG    512
#define WIMG    512
#define C1      64      // conv1 out channels
#define HMID    256     // after pool1
#define WMID    256
#define C2      128     // conv2 out channels (C_FEAT)
#define HFT     128     // after pool2
#define WFT     128
#define NROIS   256
#define ROI_FT  32
#define SPP_DIM 2688    // 128*(1+4+16)
#define FC1_OUT 256
#define NCLS    1000

typedef unsigned short ushort;
typedef __attribute__((ext_vector_type(8))) short short8;
typedef __attribute__((ext_vector_type(4))) float f32x4;

static __device__ __forceinline__ ushort f2bf(float f) {
    unsigned u = __builtin_bit_cast(unsigned, f);
    unsigned r = (u + 0x7fffu + ((u >> 16) & 1u)) >> 16;   // RNE
    return (ushort)r;
}

// ---------------------------------------------------------------------------
// Kernel W2: transpose w2 [oc][ci][3][3] fp32 -> Wt [tap][oc][ci] bf16
// ---------------------------------------------------------------------------
__global__ __launch_bounds__(256)
void k_w2t(const float* __restrict__ w2, ushort* __restrict__ Wt)
{
    int i = blockIdx.x * 256 + threadIdx.x;      // 9*128*64 = 73728
    if (i >= 9 * 128 * 64) return;
    int tap = i >> 13;
    int rem = i & 8191;
    int oc  = rem >> 6;
    int ci  = rem & 63;
    Wt[i] = f2bf(w2[(oc * 64 + ci) * 9 + tap]);
}

// ---------------------------------------------------------------------------
// Kernel W1: w1 [oc][ci][3][3] fp32 -> W1t [oc][k] bf16, k = tap*3+ci, pad 32
// ---------------------------------------------------------------------------
__global__ __launch_bounds__(256)
void k_w1t(const float* __restrict__ w1, ushort* __restrict__ W1t)
{
    int i = blockIdx.x * 256 + threadIdx.x;      // 64*32 = 2048
    if (i >= 2048) return;
    int oc = i >> 5, k = i & 31;
    float v = 0.f;
    if (k < 27) {
        int tap = k / 3, ci = k - 3 * tap;
        v = w1[oc * 27 + ci * 9 + tap];
    }
    W1t[i] = f2bf(v);
}

// ---------------------------------------------------------------------------
// Kernel A: conv1 via bf16 MFMA implicit GEMM + bias + relu + 2x2 pool.
// Block: 512 thr (8 waves: wm 0..3 x-offset, wn 0..1 oc-half). Tile 8y x 32x.
// K = 27 (3ci x 9taps) zero-padded to 32 — single MFMA chunk.
// ---------------------------------------------------------------------------
__global__ __launch_bounds__(512, 4)
void k_conv1_mfma(const float* __restrict__ x, const ushort* __restrict__ W1t,
                  const float* __restrict__ b1, ushort* __restrict__ mid)
{
    __shared__ ushort sm_x[3 * 10 * 36 + 8];     // input tile, row stride 36
    __shared__ ushort sm_o[4 * 16 * 64];         // pooled out [py][px][oc] 8KB

    const int tid = threadIdx.x;
    const int tx = blockIdx.x;    // 0..15 (32 conv cols)
    const int ty = blockIdx.y;    // 0..63 (8 conv rows)
    const int b  = blockIdx.z;

    const int cy0 = ty * 8, cx0 = tx * 32;

    // stage input halo 3 x 10 x 34 fp32 -> bf16
    for (int t = tid; t < 3 * 10 * 34; t += 512) {
        int ci  = t / 340;
        int rem = t - ci * 340;
        int r = rem / 34, c = rem - r * 34;
        int gy = cy0 - 1 + r, gx = cx0 - 1 + c;
        float v = 0.f;
        if ((unsigned)gy < (unsigned)HIMG && (unsigned)gx < (unsigned)WIMG)
            v = x[((b * C_IN + ci) * HIMG + gy) * WIMG + gx];
        sm_x[ci * 360 + r * 36 + c] = f2bf(v);
    }
    __syncthreads();

    const int l   = tid & 63;
    const int wid = tid >> 6;
    const int wm  = wid & 3;       // conv-x offset wm*8
    const int wn  = wid >> 2;      // oc offset wn*32
    const int c16 = l & 15;
    const int hi  = l >> 4;
    const int ylane = (c16 >> 1) & 1;
    const int xlane = ((c16 >> 2) << 1) | (c16 & 1);
    const int xloc  = wm * 8 + xlane;

    // per-j gather offsets: k = hi*8+j -> (tap, ci); k>=27 reads slot 0 (w=0)
    int offj[8];
    #pragma unroll
    for (int j = 0; j < 8; ++j) {
        int k = hi * 8 + j;
        int tap = k / 3, ci = k - 3 * tap;
        int dy = tap / 3, dx = tap - 3 * dy;
        offj[j] = (k < 27) ? (ci * 360 + dy * 36 + dx) : 0;
    }

    short8 bf[2];
    #pragma unroll
    for (int fn = 0; fn < 2; ++fn)
        bf[fn] = *(const short8*)(W1t + (wn * 32 + fn * 16 + c16) * 32 + hi * 8);

    f32x4 acc[4][2] = {};
    #pragma unroll
    for (int fm = 0; fm < 4; ++fm) {
        int base = (2 * fm + ylane) * 36 + xloc;
        union { ushort u[8]; short8 s; } av;
        #pragma unroll
        for (int j = 0; j < 8; ++j) av.u[j] = sm_x[offj[j] + base];
        #pragma unroll
        for (int fn = 0; fn < 2; ++fn)
            acc[fm][fn] = __builtin_amdgcn_mfma_f32_16x16x32_bf16(
                av.s, bf[fn], acc[fm][fn], 0, 0, 0);
    }

    // epilogue: pool 2x2 (lane's 4 C/D regs), stage to LDS, linear store
    const int pxl = wm * 4 + hi;   // pooled px local 0..15
    #pragma unroll
    for (int fn = 0; fn < 2; ++fn) {
        int oc = wn * 32 + fn * 16 + c16;
        float bb = b1[oc];
        #pragma unroll
        for (int fm = 0; fm < 4; ++fm) {
            f32x4 a4 = acc[fm][fn];
            float m = fmaxf(fmaxf(a4[0], a4[1]), fmaxf(a4[2], a4[3]));
            sm_o[(fm * 16 + pxl) * 64 + oc] = f2bf(fmaxf(m + bb, 0.f));
        }
    }
    __syncthreads();
    {
        int row = tid >> 7;        // 0..3 local pooled row
        int off = tid & 127;       // 128 x 16B = 2KB per row
        uint4 v = *(const uint4*)(sm_o + row * (16 * 64) + off * 8);
        int py = ty * 4 + row;
        uint4* dst = (uint4*)(mid + ((size_t)(b * HMID + py) * WMID + tx * 16) * C1) + off;
        *dst = v;
    }
}

// ---------------------------------------------------------------------------
// Kernel B: conv2 via bf16 MFMA implicit GEMM + bias + relu + 2x2 pool.
// Block: 256 thr (4 waves: wm 0..3 x-offset). Conv tile 4y x 32x, 64 oc
// (oc-group split across grid.x). acc[2][4] = 32 AGPR — fits 128-reg cap
// (R5: 64-AGPR acc forced 1 block/CU, latency-bound at 22.5% occupancy).
// LDS: halo 6 x 34 x 64ci bf16 (26 KB), XOR-swizzled 16B granules.
// ---------------------------------------------------------------------------
__global__ __launch_bounds__(256, 4)
void k_conv2_mfma(const ushort* __restrict__ mid, const ushort* __restrict__ Wt,
                  const float* __restrict__ b2, ushort* __restrict__ feat)
{
    __shared__ uint4 sm_in[204 * 8];   // 6*34 positions x 8 granules (16B = 8 ci)

    const int tid = threadIdx.x;
    const int tx  = blockIdx.x & 7;    // 0..7   (32 conv cols each)
    const int ocg = blockIdx.x >> 3;   // 0..1   (64 oc each)
    const int ty  = blockIdx.y;        // 0..63  (4 conv rows each)
    const int b   = blockIdx.z;

    const int cy0 = ty * 4, cx0 = tx * 32;

    // ---- stage halo tile (global NHWC bf16 -> LDS, swizzled) ----
    for (int t = tid; t < 204 * 8; t += 256) {
        int pos = t >> 3, g = t & 7;
        int hy = pos / 34, hx = pos - hy * 34;
        int gy = cy0 - 1 + hy, gx = cx0 - 1 + hx;
        uint4 v = make_uint4(0, 0, 0, 0);
        if ((unsigned)gy < (unsigned)HMID && (unsigned)gx < (unsigned)WMID)
            v = *(const uint4*)(mid + (((size_t)(b * HMID + gy) * WMID + gx) * C1 + g * 8));
        sm_in[pos * 8 + (g ^ (pos & 7))] = v;
    }
    __syncthreads();

    // ---- wave / lane decomposition ----
    const int l   = tid & 63;
    const int wm  = tid >> 6;       // 0..3, x-offset wm*8
    const int c16 = l & 15;
    const int hi  = l >> 4;
    const int ylane = (c16 >> 1) & 1;
    const int xlane = ((c16 >> 2) << 1) | (c16 & 1);
    const int pos00 = ylane * 34 + wm * 8 + xlane;
    const ushort* wbp = Wt + ((size_t)(ocg * 64 + c16) * 64 + 8 * hi);

    f32x4 acc[2][4] = {};

    for (int tap = 0; tap < 9; ++tap) {
        int dy = tap / 3, dx = tap - dy * 3;
        int po = pos00 + dy * 34 + dx;
        const ushort* wt = wbp + tap * 8192;
        #pragma unroll
        for (int k0 = 0; k0 < 2; ++k0) {
            short8 bfr[4];
            #pragma unroll
            for (int fn = 0; fn < 4; ++fn)
                bfr[fn] = *(const short8*)(wt + fn * 1024 + k0 * 32);
            #pragma unroll
            for (int fm = 0; fm < 2; ++fm) {
                int pos = po + fm * 68;
                int gi  = (hi + k0 * 4) ^ (pos & 7);
                short8 af = __builtin_bit_cast(short8, sm_in[pos * 8 + gi]);
                #pragma unroll
                for (int fn = 0; fn < 4; ++fn)
                    acc[fm][fn] = __builtin_amdgcn_mfma_f32_16x16x32_bf16(
                        af, bfr[fn], acc[fm][fn], 0, 0, 0);
            }
        }
    }

    // ---- epilogue: pool 2x2 in-lane -> LDS [py][px][oc64] -> linear stores ----
    __syncthreads();                       // all waves done reading sm_in
    ushort* sm_o = (ushort*)sm_in;         // reuse: 2*16*64*2B = 4KB
    const int pxl = wm * 4 + hi;
    #pragma unroll
    for (int fn = 0; fn < 4; ++fn) {
        float bb = b2[ocg * 64 + fn * 16 + c16];
        #pragma unroll
        for (int fm = 0; fm < 2; ++fm) {
            f32x4 a4 = acc[fm][fn];
            float m = fmaxf(fmaxf(a4[0], a4[1]), fmaxf(a4[2], a4[3]));
            sm_o[(fm * 16 + pxl) * 64 + fn * 16 + c16] = f2bf(fmaxf(m + bb, 0.f));
        }
    }
    __syncthreads();
    {
        int row = tid >> 7;                // 0..1 local pooled row
        int off = tid & 127;               // px = off>>3, granule = off&7
        int px  = off >> 3, g = off & 7;
        uint4 v = *(const uint4*)(sm_o + (row * 16 + px) * 64 + g * 8);
        int py = ty * 2 + row;
        uint4* dst = (uint4*)(feat + ((size_t)(b * HFT + py) * WFT + tx * 16 + px) * C2
                              + ocg * 64) + g;
        *dst = v;
    }
}

// ---------------------------------------------------------------------------
// Kernel C: ROI crop + SPP from bf16 NHWC feat. Block per ROI.
// ---------------------------------------------------------------------------
__global__ __launch_bounds__(256)
void k_roi_spp(const ushort* __restrict__ feat, const int* __restrict__ rois,
               float* __restrict__ spp)
{
    __shared__ float sm_blk[128 * 17];

    const int tid = threadIdx.x;
    const int roi = blockIdx.x;

    const int bi = rois[roi * 5 + 0];
    int xm = (int)roundf((float)rois[roi * 5 + 1] * 0.25f);
    int ym = (int)roundf((float)rois[roi * 5 + 2] * 0.25f);
    xm = min(max(xm, 0), WFT - ROI_FT);
    ym = min(max(ym, 0), HFT - ROI_FT);

    const int cpair = (tid & 63) * 2;
    const int by    = tid >> 6;

    const ushort* base = feat + ((size_t)((bi * HFT + ym + by * 8)) * WFT + xm) * C2 + cpair;

    float mm[4][2];
    #pragma unroll
    for (int bx = 0; bx < 4; ++bx) { mm[bx][0] = -INFINITY; mm[bx][1] = -INFINITY; }

    for (int y = 0; y < 8; ++y) {
        const ushort* rowp = base + (size_t)y * (WFT * C2);
        #pragma unroll
        for (int bx = 0; bx < 4; ++bx) {
            #pragma unroll
            for (int j = 0; j < 8; ++j) {
                unsigned v = *(const unsigned*)(rowp + (bx * 8 + j) * C2);
                float f0 = __builtin_bit_cast(float, v << 16);
                float f1 = __builtin_bit_cast(float, v & 0xffff0000u);
                mm[bx][0] = fmaxf(mm[bx][0], f0);
                mm[bx][1] = fmaxf(mm[bx][1], f1);
            }
        }
    }
    #pragma unroll
    for (int bx = 0; bx < 4; ++bx) {
        sm_blk[cpair * 17 + by * 4 + bx]       = mm[bx][0];
        sm_blk[(cpair + 1) * 17 + by * 4 + bx] = mm[bx][1];
    }
    __syncthreads();

    if (tid < 128) {
        float v[16];
        #pragma unroll
        for (int k = 0; k < 16; ++k) v[k] = sm_blk[tid * 17 + k];
        float* o = spp + (size_t)roi * SPP_DIM;
        #pragma unroll
        for (int k = 0; k < 16; ++k) o[640 + tid * 16 + k] = v[k];
        float g = -INFINITY;
        #pragma unroll
        for (int qy = 0; qy < 2; ++qy) {
            #pragma unroll
            for (int qx = 0; qx < 2; ++qx) {
                float q = fmaxf(fmaxf(v[(2 * qy) * 4 + 2 * qx],     v[(2 * qy) * 4 + 2 * qx + 1]),
                                fmaxf(v[(2 * qy + 1) * 4 + 2 * qx], v[(2 * qy + 1) * 4 + 2 * qx + 1]));
                o[128 + tid * 4 + qy * 2 + qx] = q;
                g = fmaxf(g, q);
            }
        }
        o[tid] = g;
    }
}

// ---------------------------------------------------------------------------
// Kernel D: FC1 + relu. 16x16 output tile per block.
// ---------------------------------------------------------------------------
__global__ __launch_bounds__(256)
void k_fc1(const float* __restrict__ spp, const float* __restrict__ w,
           const float* __restrict__ bias, float* __restrict__ h)
{
    const int col = blockIdx.x * 16 + (threadIdx.x & 15);
    const int row = blockIdx.y * 16 + (threadIdx.x >> 4);
    const float* s = spp + (size_t)row * SPP_DIM;
    float acc = bias[col];
    for (int k = 0; k < SPP_DIM; k += 4) {
        float4 s4 = *(const float4*)(s + k);
        acc = fmaf(s4.x, w[(k + 0) * FC1_OUT + col], acc);
        acc = fmaf(s4.y, w[(k + 1) * FC1_OUT + col], acc);
        acc = fmaf(s4.z, w[(k + 2) * FC1_OUT + col], acc);
        acc = fmaf(s4.w, w[(k + 3) * FC1_OUT + col], acc);
    }
    h[row * FC1_OUT + col] = fmaxf(acc, 0.f);
}

// ---------------------------------------------------------------------------
// Kernel E: FC2. 16x16 output tile per block.
// ---------------------------------------------------------------------------
__global__ __launch_bounds__(256)
void k_fc2(const float* __restrict__ h, const float* __restrict__ w,
           const float* __restrict__ bias, float* __restrict__ out)
{
    const int col = blockIdx.x * 16 + (threadIdx.x & 15);
    const int row = blockIdx.y * 16 + (threadIdx.x >> 4);
    if (col >= NCLS) return;
    const float* hr = h + (size_t)row * FC1_OUT;
    float acc = bias[col];
    for (int k = 0; k < FC1_OUT; k += 4) {
        float4 h4 = *(const float4*)(hr + k);
        acc = fmaf(h4.x, w[(k + 0) * NCLS + col], acc);
        acc = fmaf(h4.y, w[(k + 1) * NCLS + col], acc);
        acc = fmaf(h4.z, w[(k + 2) * NCLS + col], acc);
        acc = fmaf(h4.w, w[(k + 3) * NCLS + col], acc);
    }
    out[row * NCLS + col] = acc;
}

// ---------------------------------------------------------------------------
extern "C" void kernel_launch(void* const* d_in, const int* in_sizes, int n_in,
                              void* d_out, int out_size, void* d_ws, size_t ws_size,
                              hipStream_t stream)
{
    const float* x     = (const float*)d_in[0];
    const int*   rois  = (const int*)  d_in[1];
    const float* w1    = (const float*)d_in[2];
    const float* b1    = (const float*)d_in[3];
    const float* w2    = (const float*)d_in[4];
    const float* b2    = (const float*)d_in[5];
    const float* fc1_w = (const float*)d_in[6];
    const float* fc1_b = (const float*)d_in[7];
    const float* fc2_w = (const float*)d_in[8];
    const float* fc2_b = (const float*)d_in[9];
    float* out = (float*)d_out;

    // workspace: mid bf16 | Wt bf16 | W1t bf16 | feat bf16 | spp f32 | h f32
    ushort* midb  = (ushort*)d_ws;
    ushort* Wt    = midb + (size_t)NB * HMID * WMID * C1;           // 33.55M
    ushort* W1t   = Wt + 9 * 128 * 64;                              // 73728
    ushort* featb = W1t + 2048;
    float*  spp   = (float*)(featb + (size_t)NB * HFT * WFT * C2);  // 16.78M
    float*  h     = spp + (size_t)NROIS * SPP_DIM;

    k_w2t       <<<dim3(288),        256, 0, stream>>>(w2, Wt);
    k_w1t       <<<dim3(8),          256, 0, stream>>>(w1, W1t);
    k_conv1_mfma<<<dim3(16, 64, NB), 512, 0, stream>>>(x, W1t, b1, midb);
    k_conv2_mfma<<<dim3(16, 64, NB), 256, 0, stream>>>(midb, Wt, b2, featb);
    k_roi_spp   <<<dim3(NROIS),      256, 0, stream>>>(featb, rois, spp);
    k_fc1       <<<dim3(16, 16),     256, 0, stream>>>(spp, fc1_w, fc1_b, h);
    k_fc2       <<<dim3(63, 16),     256, 0, stream>>>(h, fc2_w, fc2_b, out);
}

// Round 7
// 292.574 us; speedup vs baseline: 1.4122x; 1.4122x over previous
//
#include <hip/hip_runtime.h>
#include <math.h>

// ---- problem constants ----
#define NB      8
#define C_IN    3
#define HIMG    512
#define WIMG    512
#define C1      64      // conv1 out channels
#define HMID    256     // after pool1
#define WMID    256
#define C2      128     // conv2 out channels (C_FEAT)
#define HFT     128     // after pool2
#define WFT     128
#define NROIS   256
#define ROI_FT  32
#define SPP_DIM 2688    // 128*(1+4+16)
#define FC1_OUT 256
#define NCLS    1000

typedef unsigned short ushort;
typedef __attribute__((ext_vector_type(8))) short short8;
typedef __attribute__((ext_vector_type(4))) float f32x4;

#define GLOBAL_AS __attribute__((address_space(1)))
#define LDS_AS    __attribute__((address_space(3)))

static __device__ __forceinline__ ushort f2bf(float f) {
    unsigned u = __builtin_bit_cast(unsigned, f);
    unsigned r = (u + 0x7fffu + ((u >> 16) & 1u)) >> 16;   // RNE
    return (ushort)r;
}

// ---------------------------------------------------------------------------
// Kernel W2: transpose w2 -> Wt [tap][oc][ci] bf16; also zero the zero-page.
// ---------------------------------------------------------------------------
__global__ __launch_bounds__(256)
void k_w2t(const float* __restrict__ w2, ushort* __restrict__ Wt,
           ushort* __restrict__ zp)
{
    int i = blockIdx.x * 256 + threadIdx.x;      // 9*128*64 = 73728
    if (blockIdx.x == 0 && threadIdx.x < 64) zp[threadIdx.x] = 0;
    if (i >= 9 * 128 * 64) return;
    int tap = i >> 13;
    int rem = i & 8191;
    int oc  = rem >> 6;
    int ci  = rem & 63;
    Wt[i] = f2bf(w2[(oc * 64 + ci) * 9 + tap]);
}

// ---------------------------------------------------------------------------
// Kernel W1: w1 [oc][ci][3][3] fp32 -> W1t [oc][k] bf16, k = tap*3+ci, pad 32
// ---------------------------------------------------------------------------
__global__ __launch_bounds__(256)
void k_w1t(const float* __restrict__ w1, ushort* __restrict__ W1t)
{
    int i = blockIdx.x * 256 + threadIdx.x;      // 64*32 = 2048
    if (i >= 2048) return;
    int oc = i >> 5, k = i & 31;
    float v = 0.f;
    if (k < 27) {
        int tap = k / 3, ci = k - 3 * tap;
        v = w1[oc * 27 + ci * 9 + tap];
    }
    W1t[i] = f2bf(v);
}

// ---------------------------------------------------------------------------
// Kernel A: conv1 via bf16 MFMA implicit GEMM + bias + relu + 2x2 pool.
// ---------------------------------------------------------------------------
__global__ __launch_bounds__(512, 4)
void k_conv1_mfma(const float* __restrict__ x, const ushort* __restrict__ W1t,
                  const float* __restrict__ b1, ushort* __restrict__ mid)
{
    __shared__ ushort sm_x[3 * 10 * 36 + 8];     // input tile, row stride 36
    __shared__ ushort sm_o[4 * 16 * 64];         // pooled out [py][px][oc] 8KB

    const int tid = threadIdx.x;
    const int tx = blockIdx.x;    // 0..15 (32 conv cols)
    const int ty = blockIdx.y;    // 0..63 (8 conv rows)
    const int b  = blockIdx.z;

    const int cy0 = ty * 8, cx0 = tx * 32;

    for (int t = tid; t < 3 * 10 * 34; t += 512) {
        int ci  = t / 340;
        int rem = t - ci * 340;
        int r = rem / 34, c = rem - r * 34;
        int gy = cy0 - 1 + r, gx = cx0 - 1 + c;
        float v = 0.f;
        if ((unsigned)gy < (unsigned)HIMG && (unsigned)gx < (unsigned)WIMG)
            v = x[((b * C_IN + ci) * HIMG + gy) * WIMG + gx];
        sm_x[ci * 360 + r * 36 + c] = f2bf(v);
    }
    __syncthreads();

    const int l   = tid & 63;
    const int wid = tid >> 6;
    const int wm  = wid & 3;       // conv-x offset wm*8
    const int wn  = wid >> 2;      // oc offset wn*32
    const int c16 = l & 15;
    const int hi  = l >> 4;
    const int ylane = (c16 >> 1) & 1;
    const int xlane = ((c16 >> 2) << 1) | (c16 & 1);
    const int xloc  = wm * 8 + xlane;

    int offj[8];
    #pragma unroll
    for (int j = 0; j < 8; ++j) {
        int k = hi * 8 + j;
        int tap = k / 3, ci = k - 3 * tap;
        int dy = tap / 3, dx = tap - 3 * dy;
        offj[j] = (k < 27) ? (ci * 360 + dy * 36 + dx) : 0;
    }

    short8 bf[2];
    #pragma unroll
    for (int fn = 0; fn < 2; ++fn)
        bf[fn] = *(const short8*)(W1t + (wn * 32 + fn * 16 + c16) * 32 + hi * 8);

    f32x4 acc[4][2] = {};
    #pragma unroll
    for (int fm = 0; fm < 4; ++fm) {
        int base = (2 * fm + ylane) * 36 + xloc;
        union { ushort u[8]; short8 s; } av;
        #pragma unroll
        for (int j = 0; j < 8; ++j) av.u[j] = sm_x[offj[j] + base];
        #pragma unroll
        for (int fn = 0; fn < 2; ++fn)
            acc[fm][fn] = __builtin_amdgcn_mfma_f32_16x16x32_bf16(
                av.s, bf[fn], acc[fm][fn], 0, 0, 0);
    }

    const int pxl = wm * 4 + hi;   // pooled px local 0..15
    #pragma unroll
    for (int fn = 0; fn < 2; ++fn) {
        int oc = wn * 32 + fn * 16 + c16;
        float bb = b1[oc];
        #pragma unroll
        for (int fm = 0; fm < 4; ++fm) {
            f32x4 a4 = acc[fm][fn];
            float m = fmaxf(fmaxf(a4[0], a4[1]), fmaxf(a4[2], a4[3]));
            sm_o[(fm * 16 + pxl) * 64 + oc] = f2bf(fmaxf(m + bb, 0.f));
        }
    }
    __syncthreads();
    {
        int row = tid >> 7;        // 0..3 local pooled row
        int off = tid & 127;       // 128 x 16B = 2KB per row
        uint4 v = *(const uint4*)(sm_o + row * (16 * 64) + off * 8);
        int py = ty * 4 + row;
        uint4* dst = (uint4*)(mid + ((size_t)(b * HMID + py) * WMID + tx * 16) * C1) + off;
        *dst = v;
    }
}

// ---------------------------------------------------------------------------
// Kernel B: conv2 bf16 MFMA implicit GEMM + bias + relu + 2x2 pool.
// R5 geometry: 512 thr (8 waves: wm x4, wn x2), tile 8y x 32x, 128 oc,
// acc[4][4], __launch_bounds__(512,2) (256-reg cap, no spill).
// NEW vs R5:
//  (1) staging via global_load_lds width=16: pre-swizzled per-lane SOURCE
//      address (granule g^(pos&7)), linear LDS dest, OOB lanes -> zero-page.
//  (2) B-operand register prefetch (bcur/bnxt rotation): chunk c+1's 4
//      weight loads issue before chunk c's 16 MFMAs — L2 latency hidden.
// ---------------------------------------------------------------------------
__global__ __launch_bounds__(512, 2)
void k_conv2_mfma(const ushort* __restrict__ mid, const ushort* __restrict__ Wt,
                  const float* __restrict__ b2, const ushort* __restrict__ zp,
                  ushort* __restrict__ feat)
{
    __shared__ uint4 sm_in[512 * 6];   // 48KB; slots 0..2719 = 340 pos x 8 granules

    const int tid = threadIdx.x;
    const int tx = blockIdx.x;         // 0..7   (32 conv cols each)
    const int ty = blockIdx.y;         // 0..31  (8 conv rows each)
    const int b  = blockIdx.z;

    const int cy0 = ty * 8, cx0 = tx * 32;

    // ---- stage halo tile: async global->LDS, source pre-swizzled ----
    #pragma unroll
    for (int i = 0; i < 6; ++i) {
        int t   = i * 512 + tid;
        int pos = t >> 3, g = t & 7;
        int hy  = pos / 34, hx = pos - hy * 34;
        int gy  = cy0 - 1 + hy, gx = cx0 - 1 + hx;
        bool ok = (t < 2720) && ((unsigned)gy < (unsigned)HMID)
                             && ((unsigned)gx < (unsigned)WMID);
        const ushort* src = ok
            ? mid + (((size_t)(b * HMID + gy) * WMID + gx) * C1 + (g ^ (pos & 7)) * 8)
            : zp;
        __builtin_amdgcn_global_load_lds((const GLOBAL_AS void*)src,
                                         (LDS_AS void*)&sm_in[t], 16, 0, 0);
    }
    __syncthreads();

    // ---- wave / lane decomposition ----
    const int l   = tid & 63;
    const int wid = tid >> 6;
    const int wm  = wid & 3;        // x-offset wm*8
    const int wn  = wid >> 2;       // oc-offset wn*64
    const int c16 = l & 15;
    const int hi  = l >> 4;
    const int ylane = (c16 >> 1) & 1;
    const int xlane = ((c16 >> 2) << 1) | (c16 & 1);
    const int pos00 = ylane * 34 + wm * 8 + xlane;
    const ushort* wbp = Wt + ((size_t)(wn * 64 + c16) * 64 + 8 * hi);

    f32x4 acc[4][4] = {};
    short8 bcur[4], bnxt[4];
    #pragma unroll
    for (int fn = 0; fn < 4; ++fn)
        bcur[fn] = *(const short8*)(wbp + fn * 1024);

    for (int c = 0; c < 18; ++c) {             // chunk: tap = c>>1, k0 = c&1
        int cn = (c < 17) ? c + 1 : 17;        // prefetch next chunk's weights
        const ushort* wnp = wbp + (cn >> 1) * 8192 + (cn & 1) * 32;
        #pragma unroll
        for (int fn = 0; fn < 4; ++fn)
            bnxt[fn] = *(const short8*)(wnp + fn * 1024);

        int tap = c >> 1, k0 = c & 1;
        int dy = tap / 3, dx = tap - dy * 3;
        int po = pos00 + dy * 34 + dx;
        #pragma unroll
        for (int fm = 0; fm < 4; ++fm) {
            int pos = po + fm * 68;
            int gi  = (hi + k0 * 4) ^ (pos & 7);
            short8 af = __builtin_bit_cast(short8, sm_in[pos * 8 + gi]);
            #pragma unroll
            for (int fn = 0; fn < 4; ++fn)
                acc[fm][fn] = __builtin_amdgcn_mfma_f32_16x16x32_bf16(
                    af, bcur[fn], acc[fm][fn], 0, 0, 0);
        }
        #pragma unroll
        for (int fn = 0; fn < 4; ++fn) bcur[fn] = bnxt[fn];
    }

    // ---- epilogue: pool 2x2 in-lane -> LDS [py][px][oc] -> linear stores ----
    __syncthreads();                       // all waves done reading sm_in
    ushort* sm_o = (ushort*)sm_in;         // reuse: 4*16*128*2B = 16KB
    const int pxl = wm * 4 + hi;
    #pragma unroll
    for (int fn = 0; fn < 4; ++fn) {
        int oc = wn * 64 + fn * 16 + c16;
        float bb = b2[oc];
        #pragma unroll
        for (int fm = 0; fm < 4; ++fm) {
            f32x4 a4 = acc[fm][fn];
            float m = fmaxf(fmaxf(a4[0], a4[1]), fmaxf(a4[2], a4[3]));
            sm_o[(fm * 16 + pxl) * 128 + oc] = f2bf(fmaxf(m + bb, 0.f));
        }
    }
    __syncthreads();
    const int py0 = ty * 4;
    #pragma unroll
    for (int pass = 0; pass < 2; ++pass) {
        int idx = pass * 512 + tid;        // 0..1023
        int row = idx >> 8;                // 0..3
        int off = idx & 255;               // 256 x 16B = 4KB per row
        uint4 v = *(const uint4*)(sm_o + row * (16 * 128) + off * 8);
        uint4* dst = (uint4*)(feat + ((size_t)(b * HFT + py0 + row) * WFT + tx * 16) * C2) + off;
        *dst = v;
    }
}

// ---------------------------------------------------------------------------
// Kernel C: ROI crop + SPP from bf16 NHWC feat. Block per ROI.
// ---------------------------------------------------------------------------
__global__ __launch_bounds__(256)
void k_roi_spp(const ushort* __restrict__ feat, const int* __restrict__ rois,
               float* __restrict__ spp)
{
    __shared__ float sm_blk[128 * 17];

    const int tid = threadIdx.x;
    const int roi = blockIdx.x;

    const int bi = rois[roi * 5 + 0];
    int xm = (int)roundf((float)rois[roi * 5 + 1] * 0.25f);
    int ym = (int)roundf((float)rois[roi * 5 + 2] * 0.25f);
    xm = min(max(xm, 0), WFT - ROI_FT);
    ym = min(max(ym, 0), HFT - ROI_FT);

    const int cpair = (tid & 63) * 2;
    const int by    = tid >> 6;

    const ushort* base = feat + ((size_t)((bi * HFT + ym + by * 8)) * WFT + xm) * C2 + cpair;

    float mm[4][2];
    #pragma unroll
    for (int bx = 0; bx < 4; ++bx) { mm[bx][0] = -INFINITY; mm[bx][1] = -INFINITY; }

    for (int y = 0; y < 8; ++y) {
        const ushort* rowp = base + (size_t)y * (WFT * C2);
        #pragma unroll
        for (int bx = 0; bx < 4; ++bx) {
            #pragma unroll
            for (int j = 0; j < 8; ++j) {
                unsigned v = *(const unsigned*)(rowp + (bx * 8 + j) * C2);
                float f0 = __builtin_bit_cast(float, v << 16);
                float f1 = __builtin_bit_cast(float, v & 0xffff0000u);
                mm[bx][0] = fmaxf(mm[bx][0], f0);
                mm[bx][1] = fmaxf(mm[bx][1], f1);
            }
        }
    }
    #pragma unroll
    for (int bx = 0; bx < 4; ++bx) {
        sm_blk[cpair * 17 + by * 4 + bx]       = mm[bx][0];
        sm_blk[(cpair + 1) * 17 + by * 4 + bx] = mm[bx][1];
    }
    __syncthreads();

    if (tid < 128) {
        float v[16];
        #pragma unroll
        for (int k = 0; k < 16; ++k) v[k] = sm_blk[tid * 17 + k];
        float* o = spp + (size_t)roi * SPP_DIM;
        #pragma unroll
        for (int k = 0; k < 16; ++k) o[640 + tid * 16 + k] = v[k];
        float g = -INFINITY;
        #pragma unroll
        for (int qy = 0; qy < 2; ++qy) {
            #pragma unroll
            for (int qx = 0; qx < 2; ++qx) {
                float q = fmaxf(fmaxf(v[(2 * qy) * 4 + 2 * qx],     v[(2 * qy) * 4 + 2 * qx + 1]),
                                fmaxf(v[(2 * qy + 1) * 4 + 2 * qx], v[(2 * qy + 1) * 4 + 2 * qx + 1]));
                o[128 + tid * 4 + qy * 2 + qx] = q;
                g = fmaxf(g, q);
            }
        }
        o[tid] = g;
    }
}

// ---------------------------------------------------------------------------
// Kernel D: FC1 + relu. 16x16 output tile per block.
// ---------------------------------------------------------------------------
__global__ __launch_bounds__(256)
void k_fc1(const float* __restrict__ spp, const float* __restrict__ w,
           const float* __restrict__ bias, float* __restrict__ h)
{
    const int col = blockIdx.x * 16 + (threadIdx.x & 15);
    const int row = blockIdx.y * 16 + (threadIdx.x >> 4);
    const float* s = spp + (size_t)row * SPP_DIM;
    float acc = bias[col];
    for (int k = 0; k < SPP_DIM; k += 4) {
        float4 s4 = *(const float4*)(s + k);
        acc = fmaf(s4.x, w[(k + 0) * FC1_OUT + col], acc);
        acc = fmaf(s4.y, w[(k + 1) * FC1_OUT + col], acc);
        acc = fmaf(s4.z, w[(k + 2) * FC1_OUT + col], acc);
        acc = fmaf(s4.w, w[(k + 3) * FC1_OUT + col], acc);
    }
    h[row * FC1_OUT + col] = fmaxf(acc, 0.f);
}

// ---------------------------------------------------------------------------
// Kernel E: FC2. 16x16 output tile per block.
// ---------------------------------------------------------------------------
__global__ __launch_bounds__(256)
void k_fc2(const float* __restrict__ h, const float* __restrict__ w,
           const float* __restrict__ bias, float* __restrict__ out)
{
    const int col = blockIdx.x * 16 + (threadIdx.x & 15);
    const int row = blockIdx.y * 16 + (threadIdx.x >> 4);
    if (col >= NCLS) return;
    const float* hr = h + (size_t)row * FC1_OUT;
    float acc = bias[col];
    for (int k = 0; k < FC1_OUT; k += 4) {
        float4 h4 = *(const float4*)(hr + k);
        acc = fmaf(h4.x, w[(k + 0) * NCLS + col], acc);
        acc = fmaf(h4.y, w[(k + 1) * NCLS + col], acc);
        acc = fmaf(h4.z, w[(k + 2) * NCLS + col], acc);
        acc = fmaf(h4.w, w[(k + 3) * NCLS + col], acc);
    }
    out[row * NCLS + col] = acc;
}

// ---------------------------------------------------------------------------
extern "C" void kernel_launch(void* const* d_in, const int* in_sizes, int n_in,
                              void* d_out, int out_size, void* d_ws, size_t ws_size,
                              hipStream_t stream)
{
    const float* x     = (const float*)d_in[0];
    const int*   rois  = (const int*)  d_in[1];
    const float* w1    = (const float*)d_in[2];
    const float* b1    = (const float*)d_in[3];
    const float* w2    = (const float*)d_in[4];
    const float* b2    = (const float*)d_in[5];
    const float* fc1_w = (const float*)d_in[6];
    const float* fc1_b = (const float*)d_in[7];
    const float* fc2_w = (const float*)d_in[8];
    const float* fc2_b = (const float*)d_in[9];
    float* out = (float*)d_out;

    // workspace: mid bf16 | Wt bf16 | W1t bf16 | zp | feat bf16 | spp f32 | h f32
    ushort* midb  = (ushort*)d_ws;
    ushort* Wt    = midb + (size_t)NB * HMID * WMID * C1;           // 33.55M
    ushort* W1t   = Wt + 9 * 128 * 64;                              // 73728
    ushort* zp    = W1t + 2048;                                     // 64 (128B)
    ushort* featb = zp + 64;
    float*  spp   = (float*)(featb + (size_t)NB * HFT * WFT * C2);  // 16.78M
    float*  h     = spp + (size_t)NROIS * SPP_DIM;

    k_w2t       <<<dim3(288),        256, 0, stream>>>(w2, Wt, zp);
    k_w1t       <<<dim3(8),          256, 0, stream>>>(w1, W1t);
    k_conv1_mfma<<<dim3(16, 64, NB), 512, 0, stream>>>(x, W1t, b1, midb);
    k_conv2_mfma<<<dim3(8, 32, NB),  512, 0, stream>>>(midb, Wt, b2, zp, featb);
    k_roi_spp   <<<dim3(NROIS),      256, 0, stream>>>(featb, rois, spp);
    k_fc1       <<<dim3(16, 16),     256, 0, stream>>>(spp, fc1_w, fc1_b, h);
    k_fc2       <<<dim3(63, 16),     256, 0, stream>>>(h, fc2_w, fc2_b, out);
}